// Round 2
// baseline (182.067 us; speedup 1.0000x reference)
//
#include <hip/hip_runtime.h>
#include <cmath>

// RetinaNet focal + smooth-L1 loss. Split structure (main + finalize):
// in-kernel device fences/atomic-counter finalize measured +25-30us vs
// kernel-boundary coherence (R3/R4 post-mortem). B=4, C=80 fixed.
//
// R5/R6: phase-2 was latency-bound (1200 blocks -> 4.7 waves/SIMD, PF=4 ->
// ~1.2KB in flight/CU -> ~2.5 TB/s effective on the 98MB cls stream).
// Fix: z-split phase 2 across 2 blocks (grid 2400 -> 8 blocks/CU);
// __launch_bounds__(256,8) pins VGPR<=64 so 8 waves/SIMD materializes.
// PF kept at 4 (not 6) so the ring buffer fits the 64-VGPR budget
// without scratch spills. Phase-1 assignment duplicated per z-half
// (few hundred VALU cycles - noise vs the memory win).
#define GT_CAP 64
#define PF 4                 // software-pipeline depth (outstanding loads/wave)
#define NK 10                // cls chunks per block (20 total / z-split 2)

typedef float fvec4 __attribute__((ext_vector_type(4)));

__global__ __launch_bounds__(256, 8) void retina_main(
    const float* __restrict__ cls_heads,   // (B, N, 80)
    const float* __restrict__ reg_heads,   // (B, N, 4)
    const float* __restrict__ anchors,     // (B, N, 4) — broadcast across B
    const float* __restrict__ annots,      // (B, M, 5)
    float* __restrict__ ws,                // [B] cls, [B] reg, [B] pos
    int N, int M, int B)
{
    const int b  = blockIdx.y;
    const int z  = blockIdx.z;             // phase-2 half: chunks [10z, 10z+10)
    const int n0 = blockIdx.x << 8;
    const int t  = threadIdx.x;

    __shared__ float s_ann[5 * GT_CAP];
    __shared__ float s_lab[256];
    __shared__ float s_red[12];

    const int mm = (M > GT_CAP) ? GT_CAP : M;
    for (int i = t; i < 5 * mm; i += 256)
        s_ann[i] = annots[(size_t)b * 5 * M + i];
    __syncthreads();

    // ---- phase 1: per-anchor assignment (duplicated across z — cheap VALU) ----
    float reg_acc = 0.0f;
    float pos_cnt = 0.0f;
    float label   = -1.0f;
    const int n = n0 + t;
    if (n < N) {
        // anchors identical across batch: read plane 0 (cache-served for b>0)
        const float4 a = *(const float4*)(anchors + (size_t)n * 4);
        const bool inside = (a.x > 0.0f) && (a.y > 0.0f) &&
                            (a.z < 640.0f) && (a.w < 640.0f);
        if (inside) {
            const float area_a = (a.z - a.x) * (a.w - a.y);
            float best = -3.0e38f;
            int   bi   = 0;
            bool  any  = false;
            for (int m = 0; m < mm; ++m) {
                const float gx1 = s_ann[m*5+0], gy1 = s_ann[m*5+1];
                const float gx2 = s_ann[m*5+2], gy2 = s_ann[m*5+3];
                const float gc  = s_ann[m*5+4];
                float v = -1.0f;
                if (gc >= 0.0f) {
                    any = true;
                    const float iw = fmaxf(fminf(a.z, gx2) - fmaxf(a.x, gx1), 0.0f);
                    const float ih = fmaxf(fminf(a.w, gy2) - fmaxf(a.y, gy1), 0.0f);
                    const float inter = iw * ih;
                    v = inter / (area_a + (gx2 - gx1) * (gy2 - gy1) - inter);
                }
                if (v > best) { best = v; bi = m; }   // first-max == jnp.argmax
            }
            if (any) {
                if (best < 0.4f)      label = 0.0f;
                else if (best > 0.5f) label = s_ann[bi*5+4] + 1.0f;
            }
            // reg loss + pos count only from the z==0 copy (avoid double count)
            if (z == 0 && label > 0.0f) {
                pos_cnt = 1.0f;
                const float aw = a.z - a.x, ah = a.w - a.y;
                const float acx = a.x + 0.5f * aw, acy = a.y + 0.5f * ah;
                const float gw = fmaxf(s_ann[bi*5+2] - s_ann[bi*5+0], 1.0f);
                const float gh = fmaxf(s_ann[bi*5+3] - s_ann[bi*5+1], 1.0f);
                const float gcx = s_ann[bi*5+0] + 0.5f * gw;
                const float gcy = s_ann[bi*5+1] + 0.5f * gh;
                const float tx = (gcx - acx) / aw * 10.0f;
                const float ty = (gcy - acy) / ah * 10.0f;
                const float tw = __logf(gw / aw) * 5.0f;
                const float th = __logf(gh / ah) * 5.0f;
                const float4 r = *(const float4*)(reg_heads + ((size_t)b * N + n) * 4);
                const float dx[4] = { fabsf(r.x - tx), fabsf(r.y - ty),
                                      fabsf(r.z - tw), fabsf(r.w - th) };
                #pragma unroll
                for (int j = 0; j < 4; ++j) {
                    const float x = dx[j];
                    reg_acc += (x < (1.0f / 9.0f)) ? 4.5f * x * x
                                                   : x - (1.0f / 18.0f);
                }
            }
        }
    }
    s_lab[t] = label;
    const int anyValid = __syncthreads_or(label >= 0.0f ? 1 : 0);

    // ---- phase 2: focal loss, software-pipelined depth-PF conditional loads ----
    // This z-half handles chunks [10z, 10z+10). Float index for (t, kk):
    //   4t + 1024*(10z+kk); anchor = 128z + (4t + 1024*kk')/80 with kk'
    //   the local chunk (1024*10 is a multiple of 80, so the c4 iterator
    //   start is z-independent).
    float cls_acc = 0.0f;
    if (anyValid) {
        const float* cls_base = cls_heads + ((size_t)b * N + n0) * 80
                              + (size_t)z * (1024 * NK);
        int ap = t / 20 + z * 128;            // prefetch anchor iterator
        int c4p = t - (t / 20) * 20;          // prefetch class-quad iterator
        int c4c = c4p;                        // process iterator (chunk only)
        float labb[PF];
        fvec4 pb[PF];
        #pragma unroll
        for (int k = 0; k < PF; ++k) {
            const float lab = s_lab[ap];
            fvec4 v = {0.5f, 0.5f, 0.5f, 0.5f};
            if (lab >= 0.0f) v = *(const fvec4*)(cls_base + 4 * t + 1024 * k);
            labb[k] = lab; pb[k] = v;
            ap += 12; c4p += 16; if (c4p >= 20) { c4p -= 20; ++ap; }
        }
        #pragma unroll
        for (int k = 0; k < NK; ++k) {
            const float lab = labb[k % PF];
            const fvec4 v   = pb[k % PF];
            if (k + PF < NK) {                 // refill slot with iter k+PF
                const float labn = s_lab[ap];
                fvec4 vn = {0.5f, 0.5f, 0.5f, 0.5f};
                if (labn >= 0.0f)
                    vn = *(const fvec4*)(cls_base + 4 * t + 1024 * (k + PF));
                labb[k % PF] = labn; pb[k % PF] = vn;
                ap += 12; c4p += 16; if (c4p >= 20) { c4p -= 20; ++ap; }
            }
            const float mask = (lab >= 0.0f) ? 1.0f : 0.0f;
            const float pv[4] = { v.x, v.y, v.z, v.w };
            const float cb = (float)(c4c * 4 + 1);
            float local = 0.0f;
            #pragma unroll
            for (int j = 0; j < 4; ++j) {
                const float p = fminf(fmaxf(pv[j], 1.0e-4f), 1.0f - 1.0e-4f);
                const bool  is_pos = (lab == cb + (float)j);
                const float pt     = is_pos ? p : 1.0f - p;
                const float alpha  = is_pos ? 0.25f : 0.75f;
                const float om     = 1.0f - pt;
                local += alpha * om * om * (-__logf(pt));
            }
            cls_acc += mask * local;
            c4c += 16; if (c4c >= 20) c4c -= 20;
        }
    }

    // ---- block reduction ----
    const int lane = t & 63, wid = t >> 6;
    #pragma unroll
    for (int off = 32; off > 0; off >>= 1) {
        cls_acc += __shfl_down(cls_acc, off, 64);
        reg_acc += __shfl_down(reg_acc, off, 64);
        pos_cnt += __shfl_down(pos_cnt, off, 64);
    }
    if (lane == 0) {
        s_red[wid]     = cls_acc;
        s_red[4 + wid] = reg_acc;
        s_red[8 + wid] = pos_cnt;
    }
    __syncthreads();
    if (t == 0) {
        const float c = s_red[0] + s_red[1] + s_red[2]  + s_red[3];
        const float r = s_red[4] + s_red[5] + s_red[6]  + s_red[7];
        const float p = s_red[8] + s_red[9] + s_red[10] + s_red[11];
        if (c != 0.0f) atomicAdd(&ws[b], c);
        if (r != 0.0f) atomicAdd(&ws[B + b], r);
        if (p != 0.0f) atomicAdd(&ws[2 * B + b], p);
    }
}

__global__ void retina_final(const float* __restrict__ ws,
                             float* __restrict__ out, int B)
{
    if (threadIdx.x == 0 && blockIdx.x == 0) {
        float cl = 0.0f, rl = 0.0f, nv = 0.0f;
        for (int b = 0; b < B; ++b) {
            const float pos = ws[2 * B + b];
            if (pos > 0.0f) {
                cl += ws[b]     / fmaxf(pos, 1.0f);
                rl += ws[B + b] / fmaxf(4.0f * pos, 1.0f);
                nv += 1.0f;
            }
        }
        const float n = fmaxf(nv, 1.0f);
        out[0] = cl / n;
        out[1] = rl / n;
    }
}

extern "C" void kernel_launch(void* const* d_in, const int* in_sizes, int n_in,
                              void* d_out, int out_size, void* d_ws, size_t ws_size,
                              hipStream_t stream) {
    const float* cls = (const float*)d_in[0];
    const float* reg = (const float*)d_in[1];
    const float* anc = (const float*)d_in[2];
    const float* ann = (const float*)d_in[3];

    const int B = 4;
    const int N = in_sizes[1] / (4 * B);      // 76725
    const int M = in_sizes[3] / (5 * B);      // 16
    float* ws = (float*)d_ws;

    (void)hipMemsetAsync(d_ws, 0, 12 * sizeof(float), stream);

    dim3 grid((N + 255) / 256, B, 2);
    retina_main<<<grid, 256, 0, stream>>>(cls, reg, anc, ann, ws, N, M, B);
    retina_final<<<1, 64, 0, stream>>>(ws, (float*)d_out, B);
}

// Round 3
// 175.547 us; speedup vs baseline: 1.0371x; 1.0371x over previous
//
#include <hip/hip_runtime.h>
#include <cmath>

// RetinaNet focal + smooth-L1 loss. Split structure (main + finalize):
// in-kernel device fences/atomic-counter finalize measured +25-30us vs
// kernel-boundary coherence (R3/R4 post-mortem). B=4, C=80 fixed.
//
// R5/R6: z-split phase 2 across 2 blocks (grid 2400 -> 8 blocks/CU with
// VGPR<=64 via __launch_bounds__(256,8)).
// R7 post-mortem of the 64.5us regression: predicated ring loads serialized
// twice over — (a) VGPR squeeze to 32 shortened live ranges (load->waitcnt->
// use), (b) each load's ISSUE depended on the s_lab LDS read (~120cyc) ->
// compare -> exec-mask chain. Fix: UNCONDITIONAL ring loads (mask only at
// accumulate; offset clamped to plane end as the OOB guard the predication
// used to provide), PF=4->5. Loads now issue back-to-back with no label
// dependency; FETCH rises ~15% (lab<0 rows now fetched) but BW is at 11%
// of peak — latency/MLP is the scarce resource, not bytes.
#define GT_CAP 64
#define PF 5                 // software-pipeline depth (outstanding loads/wave)
#define NK 10                // cls chunks per block (20 total / z-split 2)

typedef float fvec4 __attribute__((ext_vector_type(4)));

__global__ __launch_bounds__(256, 8) void retina_main(
    const float* __restrict__ cls_heads,   // (B, N, 80)
    const float* __restrict__ reg_heads,   // (B, N, 4)
    const float* __restrict__ anchors,     // (B, N, 4) — broadcast across B
    const float* __restrict__ annots,      // (B, M, 5)
    float* __restrict__ ws,                // [B] cls, [B] reg, [B] pos
    int N, int M, int B)
{
    const int b  = blockIdx.y;
    const int z  = blockIdx.z;             // phase-2 half: chunks [10z, 10z+10)
    const int n0 = blockIdx.x << 8;
    const int t  = threadIdx.x;

    __shared__ float s_ann[5 * GT_CAP];
    __shared__ float s_lab[256];
    __shared__ float s_red[12];

    const int mm = (M > GT_CAP) ? GT_CAP : M;
    for (int i = t; i < 5 * mm; i += 256)
        s_ann[i] = annots[(size_t)b * 5 * M + i];
    __syncthreads();

    // ---- phase 1: per-anchor assignment (duplicated across z — cheap VALU) ----
    float reg_acc = 0.0f;
    float pos_cnt = 0.0f;
    float label   = -1.0f;
    const int n = n0 + t;
    if (n < N) {
        // anchors identical across batch: read plane 0 (cache-served for b>0)
        const float4 a = *(const float4*)(anchors + (size_t)n * 4);
        const bool inside = (a.x > 0.0f) && (a.y > 0.0f) &&
                            (a.z < 640.0f) && (a.w < 640.0f);
        if (inside) {
            const float area_a = (a.z - a.x) * (a.w - a.y);
            float best = -3.0e38f;
            int   bi   = 0;
            bool  any  = false;
            for (int m = 0; m < mm; ++m) {
                const float gx1 = s_ann[m*5+0], gy1 = s_ann[m*5+1];
                const float gx2 = s_ann[m*5+2], gy2 = s_ann[m*5+3];
                const float gc  = s_ann[m*5+4];
                float v = -1.0f;
                if (gc >= 0.0f) {
                    any = true;
                    const float iw = fmaxf(fminf(a.z, gx2) - fmaxf(a.x, gx1), 0.0f);
                    const float ih = fmaxf(fminf(a.w, gy2) - fmaxf(a.y, gy1), 0.0f);
                    const float inter = iw * ih;
                    v = inter / (area_a + (gx2 - gx1) * (gy2 - gy1) - inter);
                }
                if (v > best) { best = v; bi = m; }   // first-max == jnp.argmax
            }
            if (any) {
                if (best < 0.4f)      label = 0.0f;
                else if (best > 0.5f) label = s_ann[bi*5+4] + 1.0f;
            }
            // reg loss + pos count only from the z==0 copy (avoid double count)
            if (z == 0 && label > 0.0f) {
                pos_cnt = 1.0f;
                const float aw = a.z - a.x, ah = a.w - a.y;
                const float acx = a.x + 0.5f * aw, acy = a.y + 0.5f * ah;
                const float gw = fmaxf(s_ann[bi*5+2] - s_ann[bi*5+0], 1.0f);
                const float gh = fmaxf(s_ann[bi*5+3] - s_ann[bi*5+1], 1.0f);
                const float gcx = s_ann[bi*5+0] + 0.5f * gw;
                const float gcy = s_ann[bi*5+1] + 0.5f * gh;
                const float tx = (gcx - acx) / aw * 10.0f;
                const float ty = (gcy - acy) / ah * 10.0f;
                const float tw = __logf(gw / aw) * 5.0f;
                const float th = __logf(gh / ah) * 5.0f;
                const float4 r = *(const float4*)(reg_heads + ((size_t)b * N + n) * 4);
                const float dx[4] = { fabsf(r.x - tx), fabsf(r.y - ty),
                                      fabsf(r.z - tw), fabsf(r.w - th) };
                #pragma unroll
                for (int j = 0; j < 4; ++j) {
                    const float x = dx[j];
                    reg_acc += (x < (1.0f / 9.0f)) ? 4.5f * x * x
                                                   : x - (1.0f / 18.0f);
                }
            }
        }
    }
    s_lab[t] = label;
    const int anyValid = __syncthreads_or(label >= 0.0f ? 1 : 0);

    // ---- phase 2: focal loss, depth-PF UNCONDITIONAL pipelined loads ----
    // This z-half handles chunks [10z, 10z+10). Float offset within the b-plane
    // for (t, kk): n0*80 + z*10240 + 4t + 1024*kk; anchor-in-tile =
    // (4t + 1024*kk)/80 + 128z. Offsets clamped to plane end (tail tile reads
    // last real row; masked by lab=-1). Loads carry NO label dependency.
    float cls_acc = 0.0f;
    if (anyValid) {
        const float* plane = cls_heads + (size_t)b * (size_t)N * 80;
        const unsigned base_off  = (unsigned)(n0 * 80) + (unsigned)(z * (1024 * NK));
        const unsigned plane_max = (unsigned)N * 80u - 4u;
        int ap  = t / 20 + z * 128;           // prefetch anchor iterator
        int c4p = t - (t / 20) * 20;          // prefetch class-quad iterator
        int c4c = c4p;                        // process iterator (chunk only)
        float labb[PF];
        fvec4 pb[PF];
        #pragma unroll
        for (int k = 0; k < PF; ++k) {
            unsigned off = base_off + 4u * (unsigned)t + 1024u * (unsigned)k;
            off = (off > plane_max) ? plane_max : off;
            pb[k]   = *(const fvec4*)(plane + off);
            labb[k] = s_lab[ap];
            ap += 12; c4p += 16; if (c4p >= 20) { c4p -= 20; ++ap; }
        }
        #pragma unroll
        for (int k = 0; k < NK; ++k) {
            const float lab = labb[k % PF];
            const fvec4 v   = pb[k % PF];
            if (k + PF < NK) {                 // refill slot with iter k+PF
                unsigned off = base_off + 4u * (unsigned)t + 1024u * (unsigned)(k + PF);
                off = (off > plane_max) ? plane_max : off;
                pb[k % PF]   = *(const fvec4*)(plane + off);
                labb[k % PF] = s_lab[ap];
                ap += 12; c4p += 16; if (c4p >= 20) { c4p -= 20; ++ap; }
            }
            const float mask = (lab >= 0.0f) ? 1.0f : 0.0f;
            const float pv[4] = { v.x, v.y, v.z, v.w };
            const float cb = (float)(c4c * 4 + 1);
            float local = 0.0f;
            #pragma unroll
            for (int j = 0; j < 4; ++j) {
                const float p = fminf(fmaxf(pv[j], 1.0e-4f), 1.0f - 1.0e-4f);
                const bool  is_pos = (lab == cb + (float)j);
                const float pt     = is_pos ? p : 1.0f - p;
                const float alpha  = is_pos ? 0.25f : 0.75f;
                const float om     = 1.0f - pt;
                local += alpha * om * om * (-__logf(pt));
            }
            cls_acc += mask * local;
            c4c += 16; if (c4c >= 20) c4c -= 20;
        }
    }

    // ---- block reduction ----
    const int lane = t & 63, wid = t >> 6;
    #pragma unroll
    for (int off = 32; off > 0; off >>= 1) {
        cls_acc += __shfl_down(cls_acc, off, 64);
        reg_acc += __shfl_down(reg_acc, off, 64);
        pos_cnt += __shfl_down(pos_cnt, off, 64);
    }
    if (lane == 0) {
        s_red[wid]     = cls_acc;
        s_red[4 + wid] = reg_acc;
        s_red[8 + wid] = pos_cnt;
    }
    __syncthreads();
    if (t == 0) {
        const float c = s_red[0] + s_red[1] + s_red[2]  + s_red[3];
        const float r = s_red[4] + s_red[5] + s_red[6]  + s_red[7];
        const float p = s_red[8] + s_red[9] + s_red[10] + s_red[11];
        if (c != 0.0f) atomicAdd(&ws[b], c);
        if (r != 0.0f) atomicAdd(&ws[B + b], r);
        if (p != 0.0f) atomicAdd(&ws[2 * B + b], p);
    }
}

__global__ void retina_final(const float* __restrict__ ws,
                             float* __restrict__ out, int B)
{
    if (threadIdx.x == 0 && blockIdx.x == 0) {
        float cl = 0.0f, rl = 0.0f, nv = 0.0f;
        for (int b = 0; b < B; ++b) {
            const float pos = ws[2 * B + b];
            if (pos > 0.0f) {
                cl += ws[b]     / fmaxf(pos, 1.0f);
                rl += ws[B + b] / fmaxf(4.0f * pos, 1.0f);
                nv += 1.0f;
            }
        }
        const float n = fmaxf(nv, 1.0f);
        out[0] = cl / n;
        out[1] = rl / n;
    }
}

extern "C" void kernel_launch(void* const* d_in, const int* in_sizes, int n_in,
                              void* d_out, int out_size, void* d_ws, size_t ws_size,
                              hipStream_t stream) {
    const float* cls = (const float*)d_in[0];
    const float* reg = (const float*)d_in[1];
    const float* anc = (const float*)d_in[2];
    const float* ann = (const float*)d_in[3];

    const int B = 4;
    const int N = in_sizes[1] / (4 * B);      // 76725
    const int M = in_sizes[3] / (5 * B);      // 16
    float* ws = (float*)d_ws;

    (void)hipMemsetAsync(d_ws, 0, 12 * sizeof(float), stream);

    dim3 grid((N + 255) / 256, B, 2);
    retina_main<<<grid, 256, 0, stream>>>(cls, reg, anc, ann, ws, N, M, B);
    retina_final<<<1, 64, 0, stream>>>(ws, (float*)d_out, B);
}

// Round 4
// 172.215 us; speedup vs baseline: 1.0572x; 1.0193x over previous
//
#include <hip/hip_runtime.h>
#include <cmath>

// RetinaNet focal + smooth-L1 loss. Split structure (main + finalize):
// in-kernel device fences/atomic-counter finalize measured +25-30us vs
// kernel-boundary coherence (R3/R4 post-mortem). B=4, C=80 fixed.
//
// R7/R8 post-mortem: z-split (2400 blocks) regressed 40->59-64us — it
// doubled phase-1/barrier/atomic overhead while the REAL bottleneck
// (load serialization) was untouched: __launch_bounds__(256,8) put the
// scheduler in max-pressure mode (VGPR=32; 32 and 64 are the same 8-wave
// tier, so it serialized load->waitcnt->use to save regs the occupancy
// didn't need). Per-SIMD VALU ~11%, HBM ~11%: pure MLP starvation.
// R8 fix: revert z-split (grid 1200, 20 chunks/block); batch ALL 20 chunk
// loads into a fully-unrolled register array BEFORE the consume loop;
// __launch_bounds__(256,4) (VGPR cap 128 — grid gives ~4.7 blocks/CU so
// the 128-tier's 16 waves/CU is not a constraint; VGPR up to ~115 free).
// Loads are unconditional (offset clamped to plane end; lab<0 masked at
// accumulate) so issue has NO dependency on the s_lab LDS read.
#define GT_CAP 64
#define NCH 20               // cls chunks (fvec4) per thread

typedef float fvec4 __attribute__((ext_vector_type(4)));

__global__ __launch_bounds__(256, 4) void retina_main(
    const float* __restrict__ cls_heads,   // (B, N, 80)
    const float* __restrict__ reg_heads,   // (B, N, 4)
    const float* __restrict__ anchors,     // (B, N, 4) — broadcast across B
    const float* __restrict__ annots,      // (B, M, 5)
    float* __restrict__ ws,                // [B] cls, [B] reg, [B] pos
    int N, int M, int B)
{
    const int b  = blockIdx.y;
    const int n0 = blockIdx.x << 8;
    const int t  = threadIdx.x;

    __shared__ float s_ann[5 * GT_CAP];
    __shared__ float s_lab[256];
    __shared__ float s_red[12];

    const int mm = (M > GT_CAP) ? GT_CAP : M;
    for (int i = t; i < 5 * mm; i += 256)
        s_ann[i] = annots[(size_t)b * 5 * M + i];
    __syncthreads();

    // ---- phase 1: per-anchor assignment ----
    float reg_acc = 0.0f;
    float pos_cnt = 0.0f;
    float label   = -1.0f;
    const int n = n0 + t;
    if (n < N) {
        // anchors identical across batch: read plane 0 (cache-served for b>0)
        const float4 a = *(const float4*)(anchors + (size_t)n * 4);
        const bool inside = (a.x > 0.0f) && (a.y > 0.0f) &&
                            (a.z < 640.0f) && (a.w < 640.0f);
        if (inside) {
            const float area_a = (a.z - a.x) * (a.w - a.y);
            float best = -3.0e38f;
            int   bi   = 0;
            bool  any  = false;
            for (int m = 0; m < mm; ++m) {
                const float gx1 = s_ann[m*5+0], gy1 = s_ann[m*5+1];
                const float gx2 = s_ann[m*5+2], gy2 = s_ann[m*5+3];
                const float gc  = s_ann[m*5+4];
                float v = -1.0f;
                if (gc >= 0.0f) {
                    any = true;
                    const float iw = fmaxf(fminf(a.z, gx2) - fmaxf(a.x, gx1), 0.0f);
                    const float ih = fmaxf(fminf(a.w, gy2) - fmaxf(a.y, gy1), 0.0f);
                    const float inter = iw * ih;
                    v = inter / (area_a + (gx2 - gx1) * (gy2 - gy1) - inter);
                }
                if (v > best) { best = v; bi = m; }   // first-max == jnp.argmax
            }
            if (any) {
                if (best < 0.4f)      label = 0.0f;
                else if (best > 0.5f) label = s_ann[bi*5+4] + 1.0f;
            }
            if (label > 0.0f) {
                pos_cnt = 1.0f;
                const float aw = a.z - a.x, ah = a.w - a.y;
                const float acx = a.x + 0.5f * aw, acy = a.y + 0.5f * ah;
                const float gw = fmaxf(s_ann[bi*5+2] - s_ann[bi*5+0], 1.0f);
                const float gh = fmaxf(s_ann[bi*5+3] - s_ann[bi*5+1], 1.0f);
                const float gcx = s_ann[bi*5+0] + 0.5f * gw;
                const float gcy = s_ann[bi*5+1] + 0.5f * gh;
                const float tx = (gcx - acx) / aw * 10.0f;
                const float ty = (gcy - acy) / ah * 10.0f;
                const float tw = __logf(gw / aw) * 5.0f;
                const float th = __logf(gh / ah) * 5.0f;
                const float4 r = *(const float4*)(reg_heads + ((size_t)b * N + n) * 4);
                const float dx[4] = { fabsf(r.x - tx), fabsf(r.y - ty),
                                      fabsf(r.z - tw), fabsf(r.w - th) };
                #pragma unroll
                for (int j = 0; j < 4; ++j) {
                    const float x = dx[j];
                    reg_acc += (x < (1.0f / 9.0f)) ? 4.5f * x * x
                                                   : x - (1.0f / 18.0f);
                }
            }
        }
    }
    s_lab[t] = label;
    const int anyValid = __syncthreads_or(label >= 0.0f ? 1 : 0);

    // ---- phase 2: focal loss — ALL 20 loads batched, then consume ----
    // Float offset within b-plane for (t,k): n0*80 + 4t + 1024k.
    // Quad index Q = t + 256k: anchor = Q/20, class-quad = Q%20.
    // Tail tile clamps to plane end (reads a real row; masked by lab).
    float cls_acc = 0.0f;
    if (anyValid) {
        const float* plane = cls_heads + (size_t)b * (size_t)N * 80;
        const unsigned base_off  = (unsigned)n0 * 80u + 4u * (unsigned)t;
        const unsigned plane_max = (unsigned)N * 80u - 4u;

        fvec4 pb[NCH];                       // constant-indexed -> registers
        #pragma unroll
        for (int k = 0; k < NCH; ++k) {
            unsigned off = base_off + 1024u * (unsigned)k;
            off = (off > plane_max) ? plane_max : off;
            pb[k] = *(const fvec4*)(plane + off);
        }

        int ap = t / 20;                     // anchor index within tile
        int c4 = t - (t / 20) * 20;          // class-quad within anchor
        #pragma unroll
        for (int k = 0; k < NCH; ++k) {
            const float lab  = s_lab[ap];
            const fvec4 v    = pb[k];
            const float mask = (lab >= 0.0f) ? 1.0f : 0.0f;
            const float cb   = (float)(c4 * 4 + 1);
            float local = 0.0f;
            #pragma unroll
            for (int j = 0; j < 4; ++j) {
                const float p = fminf(fmaxf(v[j], 1.0e-4f), 1.0f - 1.0e-4f);
                const bool  is_pos = (lab == cb + (float)j);
                const float pt     = is_pos ? p : 1.0f - p;
                const float alpha  = is_pos ? 0.25f : 0.75f;
                const float om     = 1.0f - pt;
                local += alpha * om * om * (-__logf(pt));
            }
            cls_acc += mask * local;
            ap += 12; c4 += 16; if (c4 >= 20) { c4 -= 20; ++ap; }
        }
    }

    // ---- block reduction ----
    const int lane = t & 63, wid = t >> 6;
    #pragma unroll
    for (int off = 32; off > 0; off >>= 1) {
        cls_acc += __shfl_down(cls_acc, off, 64);
        reg_acc += __shfl_down(reg_acc, off, 64);
        pos_cnt += __shfl_down(pos_cnt, off, 64);
    }
    if (lane == 0) {
        s_red[wid]     = cls_acc;
        s_red[4 + wid] = reg_acc;
        s_red[8 + wid] = pos_cnt;
    }
    __syncthreads();
    if (t == 0) {
        const float c = s_red[0] + s_red[1] + s_red[2]  + s_red[3];
        const float r = s_red[4] + s_red[5] + s_red[6]  + s_red[7];
        const float p = s_red[8] + s_red[9] + s_red[10] + s_red[11];
        if (c != 0.0f) atomicAdd(&ws[b], c);
        if (r != 0.0f) atomicAdd(&ws[B + b], r);
        if (p != 0.0f) atomicAdd(&ws[2 * B + b], p);
    }
}

__global__ void retina_final(const float* __restrict__ ws,
                             float* __restrict__ out, int B)
{
    if (threadIdx.x == 0 && blockIdx.x == 0) {
        float cl = 0.0f, rl = 0.0f, nv = 0.0f;
        for (int b = 0; b < B; ++b) {
            const float pos = ws[2 * B + b];
            if (pos > 0.0f) {
                cl += ws[b]     / fmaxf(pos, 1.0f);
                rl += ws[B + b] / fmaxf(4.0f * pos, 1.0f);
                nv += 1.0f;
            }
        }
        const float n = fmaxf(nv, 1.0f);
        out[0] = cl / n;
        out[1] = rl / n;
    }
}

extern "C" void kernel_launch(void* const* d_in, const int* in_sizes, int n_in,
                              void* d_out, int out_size, void* d_ws, size_t ws_size,
                              hipStream_t stream) {
    const float* cls = (const float*)d_in[0];
    const float* reg = (const float*)d_in[1];
    const float* anc = (const float*)d_in[2];
    const float* ann = (const float*)d_in[3];

    const int B = 4;
    const int N = in_sizes[1] / (4 * B);      // 76725
    const int M = in_sizes[3] / (5 * B);      // 16
    float* ws = (float*)d_ws;

    (void)hipMemsetAsync(d_ws, 0, 12 * sizeof(float), stream);

    dim3 grid((N + 255) / 256, B);
    retina_main<<<grid, 256, 0, stream>>>(cls, reg, anc, ann, ws, N, M, B);
    retina_final<<<1, 64, 0, stream>>>(ws, (float*)d_out, B);
}

// Round 7
// 170.894 us; speedup vs baseline: 1.0654x; 1.0077x over previous
//
#include <hip/hip_runtime.h>
#include <cmath>

// RetinaNet focal + smooth-L1 loss. Split structure (main + finalize).
// B=4, C=80 fixed.
//
// R8/R9 post-mortem: the compiler refuses to keep VGPR-destined loads in
// flight (ring/batch variants all emitted serial load->waitcnt->use,
// VGPR 28/32/40, ~1-2 outstanding wave-loads/CU, 850 GB/s). Hand-asm
// vmcnt batching (R9) aborted on-device — hand counts collide with
// compiler-tracked loads.
// R10/R11: global_load_lds DMA — no destination VGPRs, so regalloc cannot
// serialize it; issues stay where written; __syncthreads()'s compiler-
// emitted s_waitcnt vmcnt(0) before s_barrier is the (correct) drain.
// Block = 128 anchors, cls tile 128x80x4B = 40KB LDS -> 3 blocks/CU,
// fills of co-resident blocks overlap consumes. Per-lane src clamped to
// plane end (tail masked by lab); LDS dest is lane-linear (wave-uniform
// base + lane*16) as required. R11 = R10 resubmitted: round-6 failure was
// container infra (same signature as round 1, which ran on resubmit).
#define GT_CAP 64
#define ANCH 128             // anchors per block
#define NCH 10               // cls quad-chunks per thread (128*80/4/256)

typedef float fvec4 __attribute__((ext_vector_type(4)));

__global__ __launch_bounds__(256) void retina_main(
    const float* __restrict__ cls_heads,   // (B, N, 80)
    const float* __restrict__ reg_heads,   // (B, N, 4)
    const float* __restrict__ anchors,     // (B, N, 4) — broadcast across B
    const float* __restrict__ annots,      // (B, M, 5)
    float* __restrict__ ws,                // [B] cls, [B] reg, [B] pos
    int N, int M, int B)
{
    const int b  = blockIdx.y;
    const int n0 = blockIdx.x << 7;        // 128 anchors per block
    const int t  = threadIdx.x;

    __shared__ float s_cls[ANCH * 80];     // 40 KB DMA-staged cls tile
    __shared__ float s_ann[5 * GT_CAP];
    __shared__ float s_lab[ANCH];
    __shared__ float s_red[12];

    const int mm = (M > GT_CAP) ? GT_CAP : M;
    for (int i = t; i < 5 * mm; i += 256)
        s_ann[i] = annots[(size_t)b * 5 * M + i];
    __syncthreads();

    // ---- issue the cls-tile DMA: 10 x global_load_lds(16B) per thread ----
    // Quad q = t + 256k  ->  LDS float 4q = 4t + 1024k (per wave w, lane l:
    // byte 1024w + 4096k + 16l = uniform base + lane*16), global float
    // n0*80 + 4q (per-lane, clamped to plane end).
    {
        const float* plane = cls_heads + (size_t)b * (size_t)N * 80;
        const unsigned base_off  = (unsigned)n0 * 80u + 4u * (unsigned)t;
        const unsigned plane_max = (unsigned)N * 80u - 4u;
        #pragma unroll
        for (int k = 0; k < NCH; ++k) {
            unsigned off = base_off + 1024u * (unsigned)k;
            off = (off > plane_max) ? plane_max : off;   // tail clamp (masked)
            __builtin_amdgcn_global_load_lds(
                (const __attribute__((address_space(1))) void*)(plane + off),
                (__attribute__((address_space(3))) void*)(&s_cls[4 * t + 1024 * k]),
                16, 0, 0);
        }
    }

    // ---- phase 1: per-anchor assignment (t<128) — overlaps the DMA ----
    float reg_acc = 0.0f;
    float pos_cnt = 0.0f;
    float label   = -1.0f;
    const int n = n0 + t;
    if (t < ANCH && n < N) {
        // anchors identical across batch: read plane 0 (cache-served for b>0)
        const float4 a = *(const float4*)(anchors + (size_t)n * 4);
        const bool inside = (a.x > 0.0f) && (a.y > 0.0f) &&
                            (a.z < 640.0f) && (a.w < 640.0f);
        if (inside) {
            const float area_a = (a.z - a.x) * (a.w - a.y);
            float best = -3.0e38f;
            int   bi   = 0;
            bool  any  = false;
            for (int m = 0; m < mm; ++m) {
                const float gx1 = s_ann[m*5+0], gy1 = s_ann[m*5+1];
                const float gx2 = s_ann[m*5+2], gy2 = s_ann[m*5+3];
                const float gc  = s_ann[m*5+4];
                float v = -1.0f;
                if (gc >= 0.0f) {
                    any = true;
                    const float iw = fmaxf(fminf(a.z, gx2) - fmaxf(a.x, gx1), 0.0f);
                    const float ih = fmaxf(fminf(a.w, gy2) - fmaxf(a.y, gy1), 0.0f);
                    const float inter = iw * ih;
                    v = inter / (area_a + (gx2 - gx1) * (gy2 - gy1) - inter);
                }
                if (v > best) { best = v; bi = m; }   // first-max == jnp.argmax
            }
            if (any) {
                if (best < 0.4f)      label = 0.0f;
                else if (best > 0.5f) label = s_ann[bi*5+4] + 1.0f;
            }
            if (label > 0.0f) {
                pos_cnt = 1.0f;
                const float aw = a.z - a.x, ah = a.w - a.y;
                const float acx = a.x + 0.5f * aw, acy = a.y + 0.5f * ah;
                const float gw = fmaxf(s_ann[bi*5+2] - s_ann[bi*5+0], 1.0f);
                const float gh = fmaxf(s_ann[bi*5+3] - s_ann[bi*5+1], 1.0f);
                const float gcx = s_ann[bi*5+0] + 0.5f * gw;
                const float gcy = s_ann[bi*5+1] + 0.5f * gh;
                const float tx = (gcx - acx) / aw * 10.0f;
                const float ty = (gcy - acy) / ah * 10.0f;
                const float tw = __logf(gw / aw) * 5.0f;
                const float th = __logf(gh / ah) * 5.0f;
                const float4 r = *(const float4*)(reg_heads + ((size_t)b * N + n) * 4);
                const float dx[4] = { fabsf(r.x - tx), fabsf(r.y - ty),
                                      fabsf(r.z - tw), fabsf(r.w - th) };
                #pragma unroll
                for (int j = 0; j < 4; ++j) {
                    const float x = dx[j];
                    reg_acc += (x < (1.0f / 9.0f)) ? 4.5f * x * x
                                                   : x - (1.0f / 18.0f);
                }
            }
        }
    }
    if (t < ANCH) s_lab[t] = label;
    // barrier: compiler emits s_waitcnt vmcnt(0) lgkmcnt(0) first ->
    // all 40KB of DMA has landed in s_cls.
    const int anyValid = __syncthreads_or(label >= 0.0f ? 1 : 0);

    // ---- phase 2: focal loss consume from LDS (ds_read_b128, conflict-free) ----
    // Quad q = t + 256k: anchor = q/20, class-quad = q%20  (q < 2560).
    float cls_acc = 0.0f;
    if (anyValid) {
        int ap = t / 20;                     // anchor index within tile
        int c4 = t - (t / 20) * 20;          // class-quad within anchor
        #pragma unroll
        for (int k = 0; k < NCH; ++k) {
            const float lab  = s_lab[ap];
            const fvec4 v    = *(const fvec4*)(&s_cls[4 * t + 1024 * k]);
            const float mask = (lab >= 0.0f) ? 1.0f : 0.0f;
            const float cb   = (float)(c4 * 4 + 1);
            float local = 0.0f;
            #pragma unroll
            for (int j = 0; j < 4; ++j) {
                const float p = fminf(fmaxf(v[j], 1.0e-4f), 1.0f - 1.0e-4f);
                const bool  is_pos = (lab == cb + (float)j);
                const float pt     = is_pos ? p : 1.0f - p;
                const float alpha  = is_pos ? 0.25f : 0.75f;
                const float om     = 1.0f - pt;
                local += alpha * om * om * (-__logf(pt));
            }
            cls_acc += mask * local;
            ap += 12; c4 += 16; if (c4 >= 20) { c4 -= 20; ++ap; }
        }
    }

    // ---- block reduction ----
    const int lane = t & 63, wid = t >> 6;
    #pragma unroll
    for (int off = 32; off > 0; off >>= 1) {
        cls_acc += __shfl_down(cls_acc, off, 64);
        reg_acc += __shfl_down(reg_acc, off, 64);
        pos_cnt += __shfl_down(pos_cnt, off, 64);
    }
    if (lane == 0) {
        s_red[wid]     = cls_acc;
        s_red[4 + wid] = reg_acc;
        s_red[8 + wid] = pos_cnt;
    }
    __syncthreads();
    if (t == 0) {
        const float c = s_red[0] + s_red[1] + s_red[2]  + s_red[3];
        const float r = s_red[4] + s_red[5] + s_red[6]  + s_red[7];
        const float p = s_red[8] + s_red[9] + s_red[10] + s_red[11];
        if (c != 0.0f) atomicAdd(&ws[b], c);
        if (r != 0.0f) atomicAdd(&ws[B + b], r);
        if (p != 0.0f) atomicAdd(&ws[2 * B + b], p);
    }
}

__global__ void retina_final(const float* __restrict__ ws,
                             float* __restrict__ out, int B)
{
    if (threadIdx.x == 0 && blockIdx.x == 0) {
        float cl = 0.0f, rl = 0.0f, nv = 0.0f;
        for (int b = 0; b < B; ++b) {
            const float pos = ws[2 * B + b];
            if (pos > 0.0f) {
                cl += ws[b]     / fmaxf(pos, 1.0f);
                rl += ws[B + b] / fmaxf(4.0f * pos, 1.0f);
                nv += 1.0f;
            }
        }
        const float n = fmaxf(nv, 1.0f);
        out[0] = cl / n;
        out[1] = rl / n;
    }
}

extern "C" void kernel_launch(void* const* d_in, const int* in_sizes, int n_in,
                              void* d_out, int out_size, void* d_ws, size_t ws_size,
                              hipStream_t stream) {
    const float* cls = (const float*)d_in[0];
    const float* reg = (const float*)d_in[1];
    const float* anc = (const float*)d_in[2];
    const float* ann = (const float*)d_in[3];

    const int B = 4;
    const int N = in_sizes[1] / (4 * B);      // 76725
    const int M = in_sizes[3] / (5 * B);      // 16
    float* ws = (float*)d_ws;

    (void)hipMemsetAsync(d_ws, 0, 12 * sizeof(float), stream);

    dim3 grid((N + ANCH - 1) / ANCH, B);
    retina_main<<<grid, 256, 0, stream>>>(cls, reg, anc, ann, ws, N, M, B);
    retina_final<<<1, 64, 0, stream>>>(ws, (float*)d_out, B);
}